// Round 6
// baseline (81.148 us; speedup 1.0000x reference)
//
#include <hip/hip_runtime.h>
#include <hip/hip_fp16.h>
#include <cstdint>

#define B_SZ   1024
#define N_IN   256
#define NLAY   8
#define M_SZ   4096
#define K_SZ   16
#define NCOLS  (N_IN + 1 + NLAY * M_SZ)   // 33025
#define SCALE  4.9f
#define TPB    1024

// ---------------------------------------------------------------------------
// Prologue: pack (idx, fp16(W)) into u32 AND bank-schedule the 16 k-slots.
//
// The main kernel's gather wave-instruction at slot j reads, across its 64
// lanes (m = mblk*64 + lane), LDS banks {edge_idx[l,m,k_j(lane)] & 31}. Since
// the sum over k is commutative we may choose, per lane, ANY bijection
// k -> slot. Greedy per-(slot,bank) load balancing drives the per-instruction
// bank distribution toward the free 2-way level.
//
// One wave per group (l, mblk). Wave-lockstep execution makes the greedy
// deterministic: within a round, all 64 lanes finish their scan of the load
// counters before the single ds_add instruction executes.
// ---------------------------------------------------------------------------
__global__ __launch_bounds__(256)
void sched_pack_kernel(const int* __restrict__ edge_idx,
                       const float* __restrict__ W,
                       uint32_t* __restrict__ packed) {
    __shared__ uint32_t load[4][16][32];   // [wave][slot][bank]

    const int wave = threadIdx.x >> 6;
    const int lane = threadIdx.x & 63;
    const int g    = blockIdx.x * 4 + wave;      // 512 groups total
    const int l    = g >> 6;
    const int mblk = g & 63;
    const int m    = mblk * 64 + lane;
    const int base = (l * M_SZ + m) * K_SZ;

    // Load this lane's 16 entries (coalesced 16B loads).
    int   idxv[16];
    float wv[16];
    const int4*   ip = reinterpret_cast<const int4*>(edge_idx + base);
    const float4* wp = reinterpret_cast<const float4*>(W + base);
    #pragma unroll
    for (int j = 0; j < 4; ++j) {
        int4   ii = ip[j];
        float4 ww = wp[j];
        idxv[4*j+0] = ii.x; idxv[4*j+1] = ii.y; idxv[4*j+2] = ii.z; idxv[4*j+3] = ii.w;
        wv[4*j+0]   = ww.x; wv[4*j+1]   = ww.y; wv[4*j+2]   = ww.z; wv[4*j+3]   = ww.w;
    }

    // Zero this wave's counters.
    uint32_t* lw = &load[wave][0][0];
    #pragma unroll
    for (int s = 0; s < 8; ++s) lw[lane + s * 64] = 0;
    __syncthreads();

    uint32_t amask = 0;   // slots already used by this lane
    for (int r = 0; r < 16; ++r) {
        const int b = idxv[r] & 31;
        uint32_t bestload = 0xFFFFFFFFu;
        int      best     = 0;
        #pragma unroll
        for (int s = 0; s < 16; ++s) {
            uint32_t ld = load[wave][s][b];
            // invalidate used slots
            ld = (amask & (1u << s)) ? 0xFFFFFFFFu : ld;
            if (ld < bestload) { bestload = ld; best = s; }
        }
        amask |= 1u << best;
        __builtin_amdgcn_sched_barrier(0);            // keep scan before add
        atomicAdd(&load[wave][best][b], 1u);
        __builtin_amdgcn_sched_barrier(0);

        uint32_t p = ((uint32_t)idxv[r] & 0xFFFFu) |
                     ((uint32_t)__half_as_ushort(__float2half_rn(wv[r])) << 16);
        packed[base + best] = p;
    }
}

// ---------------------------------------------------------------------------
// Main kernel: one block = 2 batch rows; full activation history as half2 in
// LDS (132,100 B). Unchanged from the passing round-5 kernel — the packed
// table is merely slot-permuted for bank balance.
// ---------------------------------------------------------------------------
template <bool PACKED>
__global__ __launch_bounds__(TPB, 4)
void ffn_kernel(const float* __restrict__ x,
                const uint32_t* __restrict__ packed,
                const int* __restrict__ edge_idx,
                const float* __restrict__ W,
                float* __restrict__ out) {
    __shared__ uint32_t vals[NCOLS];

    const int tid = threadIdx.x;
    const int b0  = blockIdx.x * 2;
    const float* __restrict__ x0 = x + (size_t)b0 * N_IN;
    const float* __restrict__ x1 = x0 + N_IN;

    for (int j = tid; j <= N_IN; j += TPB) {
        float v0 = (j < N_IN) ? x0[j] : 1.0f;
        float v1 = (j < N_IN) ? x1[j] : 1.0f;
        __half2 h2 = __floats2half2_rn(v0, v1);
        vals[j] = *reinterpret_cast<uint32_t*>(&h2);
    }
    __syncthreads();

    const int base = N_IN + 1;
    for (int l = 0; l < NLAY; ++l) {
        for (int i = 0; i < M_SZ / TPB; ++i) {
            const int m = tid + i * TPB;
            float acc0 = 0.f, acc1 = 0.f;

            if (PACKED) {
                const uint4* p4 =
                    reinterpret_cast<const uint4*>(packed + (size_t)(l * M_SZ + m) * K_SZ);
                uint4 pw[4];
                #pragma unroll
                for (int j = 0; j < 4; ++j) pw[j] = p4[j];
                #pragma unroll
                for (int j = 0; j < 4; ++j) {
                    uint32_t words[4] = {pw[j].x, pw[j].y, pw[j].z, pw[j].w};
                    #pragma unroll
                    for (int q = 0; q < 4; ++q) {
                        uint32_t p = words[q];
                        uint32_t v = vals[p & 0xFFFFu];
                        float wf = __half2float(__ushort_as_half((unsigned short)(p >> 16)));
                        __half2 h2 = *reinterpret_cast<__half2*>(&v);
                        acc0 = fmaf(__low2float(h2), wf, acc0);
                        acc1 = fmaf(__high2float(h2), wf, acc1);
                    }
                }
            } else {
                const int4*   i4 = reinterpret_cast<const int4*>(edge_idx + (size_t)(l * M_SZ + m) * K_SZ);
                const float4* w4 = reinterpret_cast<const float4*>(W + (size_t)(l * M_SZ + m) * K_SZ);
                #pragma unroll
                for (int j = 0; j < 4; ++j) {
                    int4   ii = i4[j];
                    float4 ww = w4[j];
                    int   idxs[4] = {ii.x, ii.y, ii.z, ii.w};
                    float wts[4]  = {ww.x, ww.y, ww.z, ww.w};
                    #pragma unroll
                    for (int q = 0; q < 4; ++q) {
                        uint32_t v = vals[idxs[q]];
                        __half2 h2 = *reinterpret_cast<__half2*>(&v);
                        acc0 = fmaf(__low2float(h2), wts[q], acc0);
                        acc1 = fmaf(__high2float(h2), wts[q], acc1);
                    }
                }
            }

            float s0 = 1.0f / (1.0f + __expf(-SCALE * acc0));
            float s1 = 1.0f / (1.0f + __expf(-SCALE * acc1));

            if (l < NLAY - 1) {
                __half2 h2 = __floats2half2_rn(s0, s1);
                vals[base + l * M_SZ + m] = *reinterpret_cast<uint32_t*>(&h2);
            } else {
                out[(size_t)b0 * M_SZ + m]       = s0;
                out[(size_t)(b0 + 1) * M_SZ + m] = s1;
            }
        }
        __syncthreads();
    }
}

extern "C" void kernel_launch(void* const* d_in, const int* in_sizes, int n_in,
                              void* d_out, int out_size, void* d_ws, size_t ws_size,
                              hipStream_t stream) {
    const float* x        = (const float*)d_in[0];
    const float* W        = (const float*)d_in[1];
    const int*   edge_idx = (const int*)d_in[2];
    float*       out      = (float*)d_out;

    const int n = NLAY * M_SZ * K_SZ;  // 524288 packed words = 2 MB
    if (ws_size >= (size_t)n * sizeof(uint32_t)) {
        uint32_t* packed = (uint32_t*)d_ws;
        // 512 groups, one wave each, 4 waves per block.
        sched_pack_kernel<<<128, 256, 0, stream>>>(edge_idx, W, packed);
        ffn_kernel<true><<<B_SZ / 2, TPB, 0, stream>>>(x, packed, nullptr, nullptr, out);
    } else {
        ffn_kernel<false><<<B_SZ / 2, TPB, 0, stream>>>(x, nullptr, edge_idx, W, out);
    }
}